// Round 18
// baseline (1894.335 us; speedup 1.0000x reference)
//
#include <hip/hip_runtime.h>

// MoE block: B=4,S=2048 -> T=8192 tokens, D=2048, F=8192, E=8, K=2
#define T_TOK 8192
#define DIM   2048
#define FFN   8192
#define NE    8
#define TOPK  2

typedef unsigned short ushort_t;
typedef unsigned short ushort8  __attribute__((ext_vector_type(8)));
typedef unsigned short ushort4v __attribute__((ext_vector_type(4)));
typedef short bf16x8 __attribute__((ext_vector_type(8)));
typedef float f32x4  __attribute__((ext_vector_type(4)));

__device__ __forceinline__ ushort_t f2bf(float f) {
  unsigned int u = __float_as_uint(f);
  u += 0x7FFFu + ((u >> 16) & 1u);   // RNE
  return (ushort_t)(u >> 16);
}
__device__ __forceinline__ float bf2f(ushort_t u) {
  return __uint_as_float(((unsigned int)u) << 16);
}

// async global->LDS, 16B per lane. LDS dest wave-uniform base; HW adds lane*16.
__device__ __forceinline__ void gload16(const void* g, void* l) {
  __builtin_amdgcn_global_load_lds((const __attribute__((address_space(1))) void*)g,
                                   (__attribute__((address_space(3))) void*)l, 16, 0, 0);
}
__device__ __forceinline__ unsigned lds_off(const ushort_t* p) {
  return (unsigned)(uintptr_t)(__attribute__((address_space(3))) const ushort_t*)p;
}
// invisible LDS read: no compiler-inserted vmcnt drain before it
__device__ __forceinline__ bf16x8 ds_read128(unsigned off) {
  bf16x8 r;
  asm volatile("ds_read_b128 %0, %1" : "=v"(r) : "v"(off));
  return r;
}

// exact-erf GELU via Abramowitz-Stegun 7.1.26 (|err| <= 1.5e-7)
__device__ __forceinline__ float gelu_exact(float v) {
  float s = v * 0.70710678118654752f;
  float a = fabsf(s);
  float t = __builtin_amdgcn_rcpf(1.0f + 0.3275911f * a);
  float p = t * (0.254829592f +
            t * (-0.284496736f +
            t * (1.421413741f +
            t * (-1.453152027f +
            t * 1.061405429f))));
  float er = 1.0f - p * __expf(-a * a);
  er = copysignf(er, s);
  return 0.5f * v * (1.0f + er);
}

// ---------------- router + fused x->bf16 cast ----------------
__global__ __launch_bounds__(256) void k_router(
    const float* __restrict__ x, const float* __restrict__ rw, ushort_t* __restrict__ xbf,
    int* __restrict__ tidx, float* __restrict__ twt, int* __restrict__ counts) {
  int t = blockIdx.x;
  int tid = threadIdx.x;
  int lane = tid & 63, wave = tid >> 6;
  float acc[NE];
#pragma unroll
  for (int e = 0; e < NE; e++) acc[e] = 0.f;
  const float* xr = x + (size_t)t * DIM;
  ushort_t* xbr = xbf + (size_t)t * DIM;
#pragma unroll
  for (int it = 0; it < 2; it++) {
    int d4 = it * 1024 + tid * 4;
    float4 v = *reinterpret_cast<const float4*>(xr + d4);
    ushort4v o;
    o.x = f2bf(v.x); o.y = f2bf(v.y); o.z = f2bf(v.z); o.w = f2bf(v.w);
    *reinterpret_cast<ushort4v*>(xbr + d4) = o;
    const float* r0p = rw + (size_t)d4 * NE;
    float xv[4] = {v.x, v.y, v.z, v.w};
#pragma unroll
    for (int j = 0; j < 4; j++) {
      const float* r = r0p + j * NE;
#pragma unroll
      for (int e = 0; e < NE; e++) acc[e] += xv[j] * r[e];
    }
  }
  __shared__ float wsum[4][NE];
#pragma unroll
  for (int e = 0; e < NE; e++) {
    float v = acc[e];
#pragma unroll
    for (int off = 32; off > 0; off >>= 1) v += __shfl_down(v, off);
    if (lane == 0) wsum[wave][e] = v;
  }
  __syncthreads();
  if (tid == 0) {
    float lg[NE];
#pragma unroll
    for (int e = 0; e < NE; e++) lg[e] = wsum[0][e] + wsum[1][e] + wsum[2][e] + wsum[3][e];
    int i0 = 0; float v0 = lg[0];
#pragma unroll
    for (int e = 1; e < NE; e++) if (lg[e] > v0) { v0 = lg[e]; i0 = e; }
    int i1 = -1; float v1 = -3.4e38f;
#pragma unroll
    for (int e = 0; e < NE; e++) if (e != i0 && lg[e] > v1) { v1 = lg[e]; i1 = e; }
    float e1 = expf(v1 - v0);
    float s = 1.f + e1;
    tidx[t * 2 + 0] = i0; tidx[t * 2 + 1] = i1;
    twt[t * 2 + 0] = 1.f / s; twt[t * 2 + 1] = e1 / s;
    atomicAdd(&counts[i0], 1);
    atomicAdd(&counts[i1], 1);
  }
}

// ---------------- weight convert+transpose: fp32 [R][C] -> bf16 [C][R] ----------------
#define TT 64
__global__ __launch_bounds__(256) void k_wcvt(const float* __restrict__ in,
                                              ushort_t* __restrict__ outp, int R, int C) {
  __shared__ float t[TT][TT + 1];
  int e = blockIdx.z;
  const float* src = in + (size_t)e * R * C;
  ushort_t* dst = outp + (size_t)e * R * C;
  int r0 = blockIdx.y * TT, c0 = blockIdx.x * TT;
  int tid = threadIdx.x;
  int rr = tid >> 4;
  int c4 = tid & 15;
#pragma unroll
  for (int i = 0; i < 4; i++) {
    int r = rr + i * 16;
    float4 v = *reinterpret_cast<const float4*>(src + (size_t)(r0 + r) * C + c0 + c4 * 4);
    t[r][c4 * 4 + 0] = v.x; t[r][c4 * 4 + 1] = v.y;
    t[r][c4 * 4 + 2] = v.z; t[r][c4 * 4 + 3] = v.w;
  }
  __syncthreads();
  int c = tid >> 2, rs = tid & 3;
  ushort8 v0, v1;
#pragma unroll
  for (int i = 0; i < 8; i++) {
    v0[i] = f2bf(t[rs * 16 + i][c]);
    v1[i] = f2bf(t[rs * 16 + 8 + i][c]);
  }
  ushort_t* drow = dst + (size_t)(c0 + c) * R + r0 + rs * 16;
  *reinterpret_cast<ushort8*>(drow) = v0;
  *reinterpret_cast<ushort8*>(drow + 8) = v1;
}

__global__ void k_scan(const int* __restrict__ counts, int* __restrict__ offsets) {
  if (threadIdx.x == 0) {
    int s = 0;
    for (int e = 0; e < NE; e++) { offsets[e] = s; s += counts[e]; }
    offsets[NE] = s;
  }
}

__global__ void k_fill(const int* __restrict__ tidx, const float* __restrict__ twt,
                       const int* __restrict__ offsets, int* __restrict__ cursors,
                       int* __restrict__ ltok, float* __restrict__ lwt, int* __restrict__ ppos) {
  int t = blockIdx.x * blockDim.x + threadIdx.x;
  if (t >= T_TOK) return;
#pragma unroll
  for (int k = 0; k < TOPK; k++) {
    int e = tidx[t * 2 + k];
    int pos = atomicAdd(&cursors[e], 1);
    int p = offsets[e] + pos;
    ltok[p] = t;
    lwt[p] = twt[t * 2 + k];
    ppos[t * 2 + k] = p;
  }
}

__device__ __forceinline__ void xcd_decode(int lin, int nwg, int nx, int& xt, int& yt) {
  int q = nwg >> 3;
  int w = (lin & 7) * q + (lin >> 3);
  xt = w % nx;
  yt = w / nx;
}

// ======== 8-phase 256x256xBK64 GEMM pipeline + read-ahead (r16-proven) ========
// LDS per op: [2 slot][2 half][128 x 64] bf16 = 64 KB; A+B = 128 KB.
// XOR swizzle: chunk c of row r holds logical c^(r&7); pre-swizzled source + read offset.
// Group T (slot s=T&1), phases (2 barriers/group — hazard-audited):
//  q0: BAR; read bv(8)+A0(4)+A1(4); STA(s^1,h0,T+1); lgkm(4)[bv,A0 done; A1 fly]; MFMA q0(A0)
//  q1: BAR; read A2;  STA(s^1,h1,T+1); STB(s,h0,T+2); lgkm(4)[A1 done; A2 fly]; MFMA q1(A1)
//  q2:      read A3;  STB(s,h1,T+2);                  lgkm(4)[A2 done; A3 fly]; MFMA q2(A2)
//  q3:                                                lgkm(0)[A3 done];         MFMA q3(A3); vmcnt(4)
#define QBM 256
#define QBN 256
#define QBK 64
#define QHALF_E (128 * 64)
#define QSLOT_E (2 * QHALF_E)

#define RD_A(RR, qq)                                                                    \
  RR[0][0] = ds_read128(aoff[(qq) * 2 + 0][0] + cb);                                    \
  RR[0][1] = ds_read128(aoff[(qq) * 2 + 0][1] + cb);                                    \
  RR[1][0] = ds_read128(aoff[(qq) * 2 + 1][0] + cb);                                    \
  RR[1][1] = ds_read128(aoff[(qq) * 2 + 1][1] + cb);

#define PH_MFMA(qq, RR)                                                                 \
  __builtin_amdgcn_s_setprio(1);                                                        \
  _Pragma("unroll")                                                                     \
  for (int mf = 0; mf < 2; mf++)                                                        \
    _Pragma("unroll")                                                                   \
    for (int nf = 0; nf < 4; nf++) {                                                    \
      acc[(qq) * 2 + mf][nf] = __builtin_amdgcn_mfma_f32_16x16x32_bf16(                 \
          RR[mf][0], bv[nf][0], acc[(qq) * 2 + mf][nf], 0, 0, 0);                       \
      acc[(qq) * 2 + mf][nf] = __builtin_amdgcn_mfma_f32_16x16x32_bf16(                 \
          RR[mf][1], bv[nf][1], acc[(qq) * 2 + mf][nf], 0, 0, 0);                       \
    }                                                                                   \
  __builtin_amdgcn_s_setprio(0);

#define GEMM8_PIPE(NT_)                                                                 \
  const int NT = (NT_);                                                                 \
  STA(0, 0, 0); STA(0, 1, 0);                                                           \
  STB(0, 0, 0); STB(0, 1, 0);                                                           \
  STB(1, 0, QBK); STB(1, 1, QBK);                                                       \
  asm volatile("s_waitcnt vmcnt(4)" ::: "memory");                                      \
  for (int T = 0; T < NT; ++T) {                                                        \
    int slot = T & 1;                                                                   \
    unsigned cb = (unsigned)(slot * QSLOT_E * 2);                                       \
    bf16x8 bv[4][2], rA[2][2], rB[2][2];                                                \
    /* q0 */                                                                            \
    __builtin_amdgcn_sched_barrier(0);                                                  \
    __builtin_amdgcn_s_barrier();                                                       \
    __builtin_amdgcn_sched_barrier(0);                                                  \
    _Pragma("unroll")                                                                   \
    for (int n = 0; n < 4; n++) {                                                       \
      bv[n][0] = ds_read128(boff[n][0] + cb);                                           \
      bv[n][1] = ds_read128(boff[n][1] + cb);                                           \
    }                                                                                   \
    RD_A(rA, 0)                                                                         \
    RD_A(rB, 1)                                                                         \
    if (T + 1 < NT) { STA(slot ^ 1, 0, (T + 1) * QBK); }                                \
    __builtin_amdgcn_sched_barrier(0);                                                  \
    asm volatile("s_waitcnt lgkmcnt(4)" ::: "memory");                                  \
    __builtin_amdgcn_sched_barrier(0);                                                  \
    PH_MFMA(0, rA)                                                                      \
    /* q1 */                                                                            \
    __builtin_amdgcn_sched_barrier(0);                                                  \
    __builtin_amdgcn_s_barrier();                                                       \
    __builtin_amdgcn_sched_barrier(0);                                                  \
    RD_A(rA, 2)                                                                         \
    if (T + 1 < NT) { STA(slot ^ 1, 1, (T + 1) * QBK); }                                \
    if (T + 2 < NT) { STB(slot, 0, (T + 2) * QBK); }                                    \
    __builtin_amdgcn_sched_barrier(0);                                                  \
    asm volatile("s_waitcnt lgkmcnt(4)" ::: "memory");                                  \
    __builtin_amdgcn_sched_barrier(0);                                                  \
    PH_MFMA(1, rB)                                                                      \
    /* q2 (no barrier needed: STB(s,h1) covered by q1-BAR) */                           \
    __builtin_amdgcn_sched_barrier(0);                                                  \
    RD_A(rB, 3)                                                                         \
    if (T + 2 < NT) { STB(slot, 1, (T + 2) * QBK); }                                    \
    __builtin_amdgcn_sched_barrier(0);                                                  \
    asm volatile("s_waitcnt lgkmcnt(4)" ::: "memory");                                  \
    __builtin_amdgcn_sched_barrier(0);                                                  \
    PH_MFMA(2, rA)                                                                      \
    /* q3 (registers only) */                                                           \
    __builtin_amdgcn_sched_barrier(0);                                                  \
    asm volatile("s_waitcnt lgkmcnt(0)" ::: "memory");                                  \
    __builtin_amdgcn_sched_barrier(0);                                                  \
    PH_MFMA(3, rB)                                                                      \
    __builtin_amdgcn_sched_barrier(0);                                                  \
    if (T < NT - 2) { asm volatile("s_waitcnt vmcnt(4)" ::: "memory"); }                \
    else            { asm volatile("s_waitcnt vmcnt(0)" ::: "memory"); }                \
    __builtin_amdgcn_sched_barrier(0);                                                  \
  }

// common per-thread setup for the 8-phase kernels
#define GEMM8_SETUP()                                                                   \
  int tid = threadIdx.x;                                                                \
  int wid = tid >> 6, lane = tid & 63;                                                  \
  int wm = wid >> 2, wn = wid & 3;                                                      \
  int lm = lane & 15, lg = lane >> 4;                                                   \
  unsigned abase = lds_off(As), bbase = lds_off(Bs);                                    \
  unsigned aoff[8][2], boff[4][2];                                                      \
  _Pragma("unroll")                                                                     \
  for (int m = 0; m < 8; m++)                                                           \
    _Pragma("unroll")                                                                   \
    for (int kk = 0; kk < 2; kk++)                                                      \
      aoff[m][kk] = abase + (unsigned)((wm * QHALF_E + (m * 16 + lm) * 64 +             \
                                        (((kk * 4 + lg) ^ (lm & 7)) * 8)) * 2);         \
  _Pragma("unroll")                                                                     \
  for (int n = 0; n < 4; n++)                                                           \
    _Pragma("unroll")                                                                   \
    for (int kk = 0; kk < 2; kk++)                                                      \
      boff[n][kk] = bbase + (unsigned)(((wn >> 1) * QHALF_E +                           \
                                        ((wn & 1) * 64 + n * 16 + lm) * 64 +            \
                                        (((kk * 4 + lg) ^ (lm & 7)) * 8)) * 2);         \
  f32x4 acc[8][4];                                                                      \
  _Pragma("unroll")                                                                     \
  for (int m = 0; m < 8; m++)                                                           \
    _Pragma("unroll")                                                                   \
    for (int n = 0; n < 4; n++) acc[m][n] = (f32x4){0.f, 0.f, 0.f, 0.f};

// GEMM1: H[p,f] = gelu( gather(x)[p,:] @ w1t[e]^T + b1[e] )   w1t: [F][D] bf16
__global__ __launch_bounds__(512) void k_gemm1(
    const ushort_t* __restrict__ xbf, const ushort_t* __restrict__ w1t, const float* __restrict__ b1,
    const int* __restrict__ counts, const int* __restrict__ offsets,
    const int* __restrict__ ltok, ushort_t* __restrict__ H) {
  int e = blockIdx.z;
  int cnt = counts[e];
  int xt, yt;
  xcd_decode(blockIdx.x, (T_TOK / QBM) * (FFN / QBN), T_TOK / QBM, xt, yt);
  int row0 = xt * QBM;
  if (row0 >= cnt) return;
  int base = offsets[e];
  int col0 = yt * QBN;
  const ushort_t* Bt = w1t + (size_t)e * DIM * FFN;

  __shared__ __align__(16) ushort_t As[2 * QSLOT_E];
  __shared__ __align__(16) ushort_t Bs[2 * QSLOT_E];

  // staging sources (pre-swizzled)
  const ushort_t* aS[2][2]; const ushort_t* bS[2][2];
#pragma unroll
  for (int l = 0; l < 2; l++) {
    int c = l * 512 + threadIdx.x;
    int rr = c >> 3;
    int s8 = (c & 7) ^ (rr & 7);
#pragma unroll
    for (int h = 0; h < 2; h++) {
      int ar = min(row0 + h * 128 + rr, cnt - 1);
      aS[h][l] = xbf + (size_t)ltok[base + ar] * DIM + s8 * 8;
      bS[h][l] = Bt + (size_t)(col0 + h * 128 + rr) * DIM + s8 * 8;
    }
  }
  int swid = threadIdx.x >> 6;
  auto STA = [&](int slot, int h, int k0) {
#pragma unroll
    for (int l = 0; l < 2; l++)
      gload16(aS[h][l] + k0, As + slot * QSLOT_E + h * QHALF_E + (l * 512 + swid * 64) * 8);
  };
  auto STB = [&](int slot, int h, int k0) {
#pragma unroll
    for (int l = 0; l < 2; l++)
      gload16(bS[h][l] + k0, Bs + slot * QSLOT_E + h * QHALF_E + (l * 512 + swid * 64) * 8);
  };

  GEMM8_SETUP();
  GEMM8_PIPE(DIM / QBK);

  // epilogue
#pragma unroll
  for (int m = 0; m < 8; m++) {
#pragma unroll
    for (int n = 0; n < 4; n++) {
      int f = col0 + wn * 64 + n * 16 + lm;
      float bias = b1[e * FFN + f];
#pragma unroll
      for (int r = 0; r < 4; r++) {
        int row = row0 + wm * 128 + m * 16 + lg * 4 + r;
        if (row < cnt) {
          float v = acc[m][n][r] + bias;
          H[(size_t)(base + row) * FFN + f] = f2bf(gelu_exact(v));
        }
      }
    }
  }
}

// GEMM2: contrib[p,d] = cw[p] * ( H[p,:] @ w2t[e]^T + b2[e] )   w2t: [D][F] bf16
__global__ __launch_bounds__(512) void k_gemm2(
    const ushort_t* __restrict__ H, const ushort_t* __restrict__ w2t, const float* __restrict__ b2,
    const int* __restrict__ counts, const int* __restrict__ offsets,
    const float* __restrict__ lwt, ushort_t* __restrict__ contrib) {
  int e = blockIdx.z;
  int cnt = counts[e];
  int xt, yt;
  xcd_decode(blockIdx.x, (T_TOK / QBM) * (DIM / QBN), T_TOK / QBM, xt, yt);
  int row0 = xt * QBM;
  if (row0 >= cnt) return;
  int base = offsets[e];
  int col0 = yt * QBN;
  const ushort_t* Bt = w2t + (size_t)e * DIM * FFN;

  __shared__ __align__(16) ushort_t As[2 * QSLOT_E];
  __shared__ __align__(16) ushort_t Bs[2 * QSLOT_E];

  const ushort_t* aS[2][2]; const ushort_t* bS[2][2];
#pragma unroll
  for (int l = 0; l < 2; l++) {
    int c = l * 512 + threadIdx.x;
    int rr = c >> 3;
    int s8 = (c & 7) ^ (rr & 7);
#pragma unroll
    for (int h = 0; h < 2; h++) {
      int ar = min(row0 + h * 128 + rr, cnt - 1);
      aS[h][l] = H + (size_t)(base + ar) * FFN + s8 * 8;
      bS[h][l] = Bt + (size_t)(col0 + h * 128 + rr) * FFN + s8 * 8;
    }
  }
  int swid = threadIdx.x >> 6;
  auto STA = [&](int slot, int h, int k0) {
#pragma unroll
    for (int l = 0; l < 2; l++)
      gload16(aS[h][l] + k0, As + slot * QSLOT_E + h * QHALF_E + (l * 512 + swid * 64) * 8);
  };
  auto STB = [&](int slot, int h, int k0) {
#pragma unroll
    for (int l = 0; l < 2; l++)
      gload16(bS[h][l] + k0, Bs + slot * QSLOT_E + h * QHALF_E + (l * 512 + swid * 64) * 8);
  };

  GEMM8_SETUP();
  GEMM8_PIPE(FFN / QBK);

  // epilogue
#pragma unroll
  for (int m = 0; m < 8; m++) {
#pragma unroll
    for (int n = 0; n < 4; n++) {
      int d = col0 + wn * 64 + n * 16 + lm;
      float bias = b2[e * DIM + d];
#pragma unroll
      for (int r = 0; r < 4; r++) {
        int row = row0 + wm * 128 + m * 16 + lg * 4 + r;
        if (row < cnt) {
          float v = (acc[m][n][r] + bias) * lwt[base + row];
          contrib[(size_t)(base + row) * DIM + d] = f2bf(v);
        }
      }
    }
  }
}

// ---------------- combine: out = x + contrib[p0] + contrib[p1] ----------------
__global__ void k_combine(const float* __restrict__ x, const ushort_t* __restrict__ contrib,
                          const int* __restrict__ ppos, float* __restrict__ out) {
  int i = blockIdx.x * blockDim.x + threadIdx.x;
  int t = i / (DIM / 4);
  int dq = i % (DIM / 4);
  int p0 = ppos[t * 2 + 0], p1 = ppos[t * 2 + 1];
  float4 xv = reinterpret_cast<const float4*>(x)[i];
  ushort4v c0 = reinterpret_cast<const ushort4v*>(contrib + (size_t)p0 * DIM)[dq];
  ushort4v c1 = reinterpret_cast<const ushort4v*>(contrib + (size_t)p1 * DIM)[dq];
  float4 o;
  o.x = xv.x + bf2f(c0.x) + bf2f(c1.x);
  o.y = xv.y + bf2f(c0.y) + bf2f(c1.y);
  o.z = xv.z + bf2f(c0.z) + bf2f(c1.z);
  o.w = xv.w + bf2f(c0.w) + bf2f(c1.w);
  reinterpret_cast<float4*>(out)[i] = o;
}

extern "C" void kernel_launch(void* const* d_in, const int* in_sizes, int n_in,
                              void* d_out, int out_size, void* d_ws, size_t ws_size,
                              hipStream_t stream) {
  const float* x  = (const float*)d_in[0];
  const float* rw = (const float*)d_in[1];
  const float* w1 = (const float*)d_in[2];
  const float* b1 = (const float*)d_in[3];
  const float* w2 = (const float*)d_in[4];
  const float* b2 = (const float*)d_in[5];
  float* out = (float*)d_out;
  char* ws = (char*)d_ws;

  const size_t MB = 1u << 20;
  int*   counts  = (int*)(ws);
  int*   offsets = (int*)(ws + 64);
  int*   cursors = (int*)(ws + 128);
  int*   tidx    = (int*)(ws + 1 * MB);
  float* twt     = (float*)(ws + 2 * MB);
  int*   ltok    = (int*)(ws + 3 * MB);
  float* lwt     = (float*)(ws + 4 * MB);
  int*   ppos    = (int*)(ws + 5 * MB);
  // overlaid big buffers (lifetimes disjoint where they overlap):
  ushort_t* xbf     = (ushort_t*)(ws + 8 * MB);     // 32 MB, live router..gemm1
  ushort_t* contrib = (ushort_t*)(ws + 8 * MB);     // 64 MB, live gemm2..combine (xbf dead)
  ushort_t* Hbuf    = (ushort_t*)(ws + 72 * MB);    // 256 MB, live gemm1..gemm2
  ushort_t* w1t     = (ushort_t*)(ws + 328 * MB);   // 256 MB, live wcvt1..gemm1
  ushort_t* w2t     = (ushort_t*)(ws + 328 * MB);   // 256 MB, live wcvt2..gemm2 (after gemm1)
  const size_t NEED = 584 * MB;
  if (ws_size < NEED) {
    hipMemsetAsync(d_out, 0, (size_t)out_size * sizeof(float), stream);
    return;
  }

  hipMemsetAsync(ws, 0, 256, stream);  // counts + cursors
  k_router<<<T_TOK, 256, 0, stream>>>(x, rw, xbf, tidx, twt, counts);
  k_scan<<<1, 64, 0, stream>>>(counts, offsets);
  k_fill<<<T_TOK / 256, 256, 0, stream>>>(tidx, twt, offsets, cursors, ltok, lwt, ppos);
  // w1: [E][D][F] fp32 -> w1t [E][F][D] bf16
  k_wcvt<<<dim3(FFN / TT, DIM / TT, NE), 256, 0, stream>>>(w1, w1t, DIM, FFN);
  k_gemm1<<<dim3((T_TOK / QBM) * (FFN / QBN), 1, NE), 512, 0, stream>>>(xbf, w1t, b1, counts, offsets, ltok, Hbuf);
  // w2: [E][F][D] fp32 -> w2t [E][D][F] bf16  (after gemm1; reuses w1t region)
  k_wcvt<<<dim3(DIM / TT, FFN / TT, NE), 256, 0, stream>>>(w2, w2t, FFN, DIM);
  k_gemm2<<<dim3((T_TOK / QBM) * (DIM / QBN), 1, NE), 512, 0, stream>>>(Hbuf, w2t, b2, counts, offsets, lwt, contrib);
  k_combine<<<dim3((T_TOK * (size_t)DIM / 4) / 256), 256, 0, stream>>>(x, contrib, ppos, out);
}